// Round 12
// baseline (48.736 us; speedup 1.0000x reference)
//
#include <hip/hip_runtime.h>

#define NB 8
#define NS 2048
#define ND 512
#define NKD 64
#define NM (NB*NS)

typedef _Float16 f16x8 __attribute__((ext_vector_type(8)));
typedef float f32x4 __attribute__((ext_vector_type(4)));

// ---------------------------------------------------------------------------
// Workspace layout (f16):
//   wfrag : 20480 f16x8 (327,680 B)
//   qkri  : [p 0..3][m][64] f16  (8,388,608 B)   p: qr,qi,kr,ki
//   vT    : [b][d 0..63][s 0..NS) f16 (2,097,152 B)
// ---------------------------------------------------------------------------

__global__ __launch_bounds__(256) void wprep_kernel(
    const float* __restrict__ w0, const float* __restrict__ w1,
    const float* __restrict__ w2, const float* __restrict__ w3,
    const float* __restrict__ w4,
    f16x8* __restrict__ wfrag)
{
    const int t = blockIdx.x * 256 + threadIdx.x;     // 0..20479
    const int p    = t >> 12;
    const int nf   = (t >> 10) & 3;
    const int kt   = (t >> 6) & 15;
    const int lane = t & 63;
    const float* __restrict__ W = (p==0)?w0:(p==1)?w1:(p==2)?w2:(p==3)?w3:w4;
    const int n  = nf*16 + (lane & 15);
    const int k0 = kt*32 + (lane >> 4)*8;
    f16x8 v;
    #pragma unroll
    for (int j = 0; j < 8; ++j)
        v[j] = (_Float16)W[(size_t)(k0 + j)*NKD + n];
    wfrag[t] = v;
}

// ---------------------------------------------------------------------------
// Kernel A: FUSED projection GEMM (unchanged from round 11).
// ---------------------------------------------------------------------------
__global__ __launch_bounds__(256) void proj_mfma(
    const float* __restrict__ x,
    const f16x8* __restrict__ wfrag,
    const float* __restrict__ b0, const float* __restrict__ b1,
    const float* __restrict__ b2, const float* __restrict__ b3,
    const float* __restrict__ b4,
    const float* __restrict__ p0, const float* __restrict__ p1,
    const float* __restrict__ p2, const float* __restrict__ p3,
    _Float16* __restrict__ qkri,
    _Float16* __restrict__ vT)
{
    __shared__ __align__(16) _Float16 vtile[64][40];

    const int w    = threadIdx.x >> 6;
    const int lane = threadIdx.x & 63;
    const int half = w & 1;
    const int mt   = blockIdx.x*2 + (w >> 1);
    const int m0   = mt * 16;

    const int col   = lane & 15;
    const int rbase = (lane >> 4) << 2;

    const float* __restrict__ xrow = x + (size_t)(m0 + col) * ND + (lane >> 4)*8;
    const f16x8* __restrict__ wf   = wfrag + lane;
    const int pa = half * 2;

    f32x4 acc[2][4], accv[2];
    #pragma unroll
    for (int pp = 0; pp < 2; ++pp)
        #pragma unroll
        for (int nf = 0; nf < 4; ++nf) acc[pp][nf] = (f32x4){0.f,0.f,0.f,0.f};
    accv[0] = (f32x4){0.f,0.f,0.f,0.f};
    accv[1] = (f32x4){0.f,0.f,0.f,0.f};

    for (int kt = 0; kt < 16; ++kt) {
        float4 xa = *(const float4*)(xrow + kt*32);
        float4 xb = *(const float4*)(xrow + kt*32 + 4);
        f16x8 a;
        a[0]=(_Float16)xa.x; a[1]=(_Float16)xa.y;
        a[2]=(_Float16)xa.z; a[3]=(_Float16)xa.w;
        a[4]=(_Float16)xb.x; a[5]=(_Float16)xb.y;
        a[6]=(_Float16)xb.z; a[7]=(_Float16)xb.w;
        #pragma unroll
        for (int pp = 0; pp < 2; ++pp)
            #pragma unroll
            for (int nf = 0; nf < 4; ++nf) {
                f16x8 b = wf[((pa + pp)*4 + nf)*1024 + kt*64];
                acc[pp][nf] = __builtin_amdgcn_mfma_f32_16x16x32_f16(a, b, acc[pp][nf], 0, 0, 0);
            }
        #pragma unroll
        for (int j = 0; j < 2; ++j) {
            const int nfv = half*2 + j;
            f16x8 b = wf[(16 + nfv)*1024 + kt*64];
            accv[j] = __builtin_amdgcn_mfma_f32_16x16x32_f16(a, b, accv[j], 0, 0, 0);
        }
    }

    const float* biases[5] = {b0, b1, b2, b3, b4};
    const float* poss[4]   = {p0, p1, p2, p3};

    #pragma unroll
    for (int pp = 0; pp < 2; ++pp) {
        const int p = pa + pp;
        _Float16* ob = qkri + ((size_t)p*NM + m0) * NKD;
        #pragma unroll
        for (int nf = 0; nf < 4; ++nf) {
            const int c = nf*16 + col;
            const float bb = biases[p][c];
            #pragma unroll
            for (int r = 0; r < 4; ++r) {
                const int mm = rbase + r;
                const int s  = (m0 + mm) & (NS - 1);
                float t = acc[pp][nf][r] + bb;
                if (p < 2) t = t * 0.125f + poss[p][s*NKD + c];
                else       t = t + poss[p][s*NKD + c];
                ob[(size_t)mm*NKD + c] = (_Float16)t;
            }
        }
    }

    #pragma unroll
    for (int j = 0; j < 2; ++j) {
        const int c = (half*2 + j)*16 + col;
        const float bb = b4[c];
        #pragma unroll
        for (int r = 0; r < 4; ++r) {
            const int sl = (w >> 1)*16 + rbase + r;
            vtile[c][sl] = (_Float16)(accv[j][r] + bb);
        }
    }
    __syncthreads();
    {
        const int t   = threadIdx.x;
        const int d   = t >> 2;
        const int sc  = (t & 3) * 8;
        const int mblk = blockIdx.x * 32;
        const int bidx = mblk >> 11;
        const int sb   = mblk & (NS - 1);
        f16x8 vv = *(const f16x8*)&vtile[d][sc];
        *(f16x8*)&vT[((size_t)bidx*NKD + d)*NS + sb + sc] = vv;
    }
}

// ---------------------------------------------------------------------------
// Kernel B: banded causal attention — R10 algebra + LDS-staged operands.
// grid = 1024 blocks (1-D, XCD-aware decode: b = bid&7, ix = bid>>3) x 256.
// Staging: K window (144 rows x 128B, kr+ki) and V window (64 d-rows x 160)
// loaded ROW-CONTIGUOUSLY (consecutive tid -> consecutive 16B of one row) so
// every 128B line is fetched once and fully used; MFMA frags then read LDS.
// olds overlays the dead krs region after barrier 2.  LDS total 70,912 B ->
// 2 blocks/CU.
// ---------------------------------------------------------------------------
#define SST 164    /* f32 score stride */
#define OST 68     /* f32 O-partial stride */
#define VSTR 184   /* f16 stride of vs rows: 92 words %32 = 28 -> 2-way */

__global__ __launch_bounds__(256) void attn_mfma(
    const _Float16* __restrict__ qkri,
    const _Float16* __restrict__ vT,
    const float* __restrict__ temp,
    float* __restrict__ out)
{
    extern __shared__ __align__(16) char smem[];
    _Float16* krs = (_Float16*)smem;              // 9216 f16 (18,432 B)
    _Float16* kis = krs + 9216;                   // 9216 f16
    _Float16* vs  = kis + 9216;                   // 64*VSTR = 11776 f16 (23,552 B)
    float*    scf = (float*)(vs + 11776);         // 16*SST f32 (10,496 B)
    float*    olds = (float*)smem;                // overlay on krs (13,056 B)

    const int tid  = threadIdx.x;
    const int w    = tid >> 6;
    const int lane = tid & 63;
    const int bid  = blockIdx.x;
    const int b    = bid & 7;                     // XCD-aware: same b -> same XCD
    const int ix   = bid >> 3;
    const int i0   = ix * 16;
    const int jb   = i0 - 128;

    const _Float16* __restrict__ qr_g = qkri + ((size_t)0*NM + (size_t)b*NS)*NKD;
    const _Float16* __restrict__ qi_g = qkri + ((size_t)1*NM + (size_t)b*NS)*NKD;
    const _Float16* __restrict__ kr_g = qkri + ((size_t)2*NM + (size_t)b*NS)*NKD;
    const _Float16* __restrict__ ki_g = qkri + ((size_t)3*NM + (size_t)b*NS)*NKD;
    const _Float16* __restrict__ vT_b = vT + (size_t)b*NKD*NS;

    const f16x8 zf = {};
    const int col  = lane & 15;
    const int seg  = lane >> 4;
    const int qg4  = seg * 4;

    // ---- stage K (kr,ki): 2*1152 items, row-contiguous reads ----
    for (int idx = tid; idx < 2*1152; idx += 256) {
        const int mtx = (idx >= 1152) ? 1 : 0;
        const int r   = idx - mtx*1152;
        const int jj  = r >> 3;                   // window row 0..143
        const int c8  = r & 7;                    // 16B chunk in row
        const int row = jb + jj;
        f16x8 v = {};
        if (row >= 0)
            v = *(const f16x8*)&(mtx ? ki_g : kr_g)[(size_t)row*NKD + c8*8];
        const int t  = jj >> 4, rl = jj & 15;
        const int kt = c8 >> 2, lh = c8 & 3;
        ((f16x8*)(mtx ? kis : krs))[(t*2 + kt)*64 + rl + 16*lh] = v;
    }
    // ---- stage V: 64 d-rows x 20 chunks, row-contiguous reads ----
    for (int idx = tid; idx < 64*20; idx += 256) {
        const int d = idx / 20, c = idx % 20;
        const int s = jb + c*8;
        f16x8 v = {};
        if (s >= 0 && s <= NS - 8)
            v = *(const f16x8*)&vT_b[(size_t)d*NS + s];
        *(f16x8*)&vs[d*VSTR + c*8] = v;
    }

    // ---- Q fragments (imag negated) ----
    const int qrow = i0 + col;
    const int d0   = seg * 8;
    f16x8 aqr[2], aqi[2];
    #pragma unroll
    for (int kt = 0; kt < 2; ++kt) {
        aqr[kt] = *(const f16x8*)&qr_g[(size_t)qrow*NKD + kt*32 + d0];
        f16x8 qi8 = *(const f16x8*)&qi_g[(size_t)qrow*NKD + kt*32 + d0];
        aqi[kt] = -qi8;
    }
    __syncthreads();

    // ---- Phase 1: QK^T + mask for owned tiles -> scf ----
    const float sT  = 0.125f * temp[0];
    const int jrmin = -jb;
    const int tA = (w == 0) ? 0 : (2*w + 1);
    const int tB = 2*w + 2;

    for (int t = tA; t <= tB; ++t) {
        f16x8 bkr0 = ((f16x8*)krs)[(t*2+0)*64 + lane];
        f16x8 bkr1 = ((f16x8*)krs)[(t*2+1)*64 + lane];
        f16x8 bki0 = ((f16x8*)kis)[(t*2+0)*64 + lane];
        f16x8 bki1 = ((f16x8*)kis)[(t*2+1)*64 + lane];
        f32x4 acc = (f32x4){0.f,0.f,0.f,0.f};
        acc = __builtin_amdgcn_mfma_f32_16x16x32_f16(aqr[0], bkr0, acc, 0,0,0);
        acc = __builtin_amdgcn_mfma_f32_16x16x32_f16(aqr[1], bkr1, acc, 0,0,0);
        acc = __builtin_amdgcn_mfma_f32_16x16x32_f16(aqi[0], bki0, acc, 0,0,0);
        acc = __builtin_amdgcn_mfma_f32_16x16x32_f16(aqi[1], bki1, acc, 0,0,0);
        const int jr = 16*t + col;
        #pragma unroll
        for (int r = 0; r < 4; ++r) {
            const int row16 = qg4 + r;
            const bool okm = (jr >= row16) && (jr <= 128 + row16) && (jr >= jrmin);
            scf[(qg4 + r)*SST + jr] = okm ? acc[r]*sT : -1e30f;
        }
    }
    if (w == 0) {
        #pragma unroll
        for (int r = 0; r < 4; ++r)
            scf[(qg4 + r)*SST + 144 + col] = -1e30f;
    }
    __syncthreads();

    // ---- Phase 2: per-lane softmax stats ----
    const float* srow = &scf[col*SST + seg*40];
    float4 vv[10];
    float m = -3e38f;
    #pragma unroll
    for (int c = 0; c < 10; ++c) {
        vv[c] = *(const float4*)(srow + 4*c);
        m = fmaxf(m, fmaxf(fmaxf(vv[c].x, vv[c].y), fmaxf(vv[c].z, vv[c].w)));
    }
    m = fmaxf(m, __shfl_xor(m, 16));
    m = fmaxf(m, __shfl_xor(m, 32));
    float l = 0.f;
    #pragma unroll
    for (int c = 0; c < 10; ++c) {
        l += __expf(vv[c].x - m) + __expf(vv[c].y - m)
           + __expf(vv[c].z - m) + __expf(vv[c].w - m);
    }
    l += __shfl_xor(l, 16);
    l += __shfl_xor(l, 32);
    const float inv = 1.0f / l;

    // ---- PV: wave w -> k-step w; w0 also k-step 4; V frags from LDS ----
    f32x4 oacc[4];
    #pragma unroll
    for (int nf = 0; nf < 4; ++nf) oacc[nf] = (f32x4){0.f,0.f,0.f,0.f};

    #pragma unroll
    for (int pass = 0; pass < 2; ++pass) {
        const int kt = (pass == 0) ? w : 4;
        if (pass == 1 && w != 0) break;
        const int sb = 32*kt + seg*8;
        float4 e0 = *(const float4*)&scf[col*SST + sb];
        float4 e1 = *(const float4*)&scf[col*SST + sb + 4];
        f16x8 a;
        a[0] = (_Float16)(__expf(e0.x - m) * inv);
        a[1] = (_Float16)(__expf(e0.y - m) * inv);
        a[2] = (_Float16)(__expf(e0.z - m) * inv);
        a[3] = (_Float16)(__expf(e0.w - m) * inv);
        a[4] = (_Float16)(__expf(e1.x - m) * inv);
        a[5] = (_Float16)(__expf(e1.y - m) * inv);
        a[6] = (_Float16)(__expf(e1.z - m) * inv);
        a[7] = (_Float16)(__expf(e1.w - m) * inv);
        #pragma unroll
        for (int nf = 0; nf < 4; ++nf) {
            const int d = nf*16 + col;
            f16x8 bv = *(const f16x8*)&vs[d*VSTR + sb];
            oacc[nf] = __builtin_amdgcn_mfma_f32_16x16x32_f16(a, bv, oacc[nf], 0,0,0);
        }
    }

    // ---- publish partials into overlay (krs dead after barrier 2) ----
    if (w > 0) {
        #pragma unroll
        for (int nf = 0; nf < 4; ++nf)
            #pragma unroll
            for (int r = 0; r < 4; ++r)
                olds[(w-1)*16*OST + (qg4 + r)*OST + nf*16 + col] = oacc[nf][r];
    }
    __syncthreads();
    if (w == 0) {
        float* ob = out + ((size_t)b*NS + i0)*NKD;
        #pragma unroll
        for (int nf = 0; nf < 4; ++nf)
            #pragma unroll
            for (int r = 0; r < 4; ++r) {
                const int idx = (qg4 + r)*OST + nf*16 + col;
                const float v = oacc[nf][r] + olds[idx]
                              + olds[16*OST + idx] + olds[2*16*OST + idx];
                ob[(size_t)(qg4 + r)*NKD + nf*16 + col] = v;
            }
    }
}

#define ATTN_LDS 70912

// ---------------------------------------------------------------------------
extern "C" void kernel_launch(void* const* d_in, const int* in_sizes, int n_in,
                              void* d_out, int out_size, void* d_ws, size_t ws_size,
                              hipStream_t stream)
{
    const float* x    = (const float*)d_in[0];
    const float* w0   = (const float*)d_in[1];
    const float* b0   = (const float*)d_in[2];
    const float* w1   = (const float*)d_in[3];
    const float* b1   = (const float*)d_in[4];
    const float* w2   = (const float*)d_in[5];
    const float* b2   = (const float*)d_in[6];
    const float* w3   = (const float*)d_in[7];
    const float* b3   = (const float*)d_in[8];
    const float* w4   = (const float*)d_in[9];
    const float* b4   = (const float*)d_in[10];
    const float* p0   = (const float*)d_in[11];
    const float* p1   = (const float*)d_in[12];
    const float* p2   = (const float*)d_in[13];
    const float* p3   = (const float*)d_in[14];
    const float* temp = (const float*)d_in[15];

    char* ws = (char*)d_ws;
    f16x8*    wfrag = (f16x8*)ws;                              // 327,680 B
    _Float16* qkri  = (_Float16*)(ws + 327680);                // 8,388,608 B
    _Float16* vT    = (_Float16*)(ws + 327680 + 8388608);      // 2,097,152 B

    wprep_kernel<<<80, 256, 0, stream>>>(w0, w1, w2, w3, w4, wfrag);

    proj_mfma<<<512, 256, 0, stream>>>(x, wfrag,
                                       b0, b1, b2, b3, b4,
                                       p0, p1, p2, p3, qkri, vT);

    hipFuncSetAttribute((const void*)attn_mfma,
                        hipFuncAttributeMaxDynamicSharedMemorySize, ATTN_LDS);
    attn_mfma<<<1024, 256, ATTN_LDS, stream>>>(qkri, vT, temp, (float*)d_out);
}